// Round 10
// baseline (181.748 us; speedup 1.0000x reference)
//
#include <hip/hip_runtime.h>

// Shapes (fixed by the problem)
#define BN      8
#define NTOK    1024
#define DIM     512
#define INNER   512
#define CIN     128
#define SPATIAL 13824   // 24*24*24
#define HALF_F  6912    // SPATIAL/2 floats
#define HALF_V4 1728    // HALF_F/4 float4

// native clang vector type: __builtin_nontemporal_store rejects HIP's float4
// (a HIP_vector_type class). Same 16-byte layout.
typedef float floatx4 __attribute__((ext_vector_type(4)));

// ---------------------------------------------------------------------------
// Kernel A: partial pooled sums. Block = (pair, half), pair=b*128+c in [0,1024),
// half in {0,1}. Each block reads the mri half-segment AND the pet half-segment
// (27 KB each) -> TWO independent address streams per thread, 4 accumulators.
// Writes pooledP[mod][pair][half] (already scaled by 1/SPATIAL; halves add to
// the full mean in vt_kernel).
// R7 lesson: single-stream 4-acc unroll was neutral (~40us). This probes
// whether cross-stream MLP moves the needle; if not, concurrency isn't the
// limiter and ~2.8 TB/s is the effective read ceiling here.
// ---------------------------------------------------------------------------
__global__ __launch_bounds__(256) void pool_kernel(const float* __restrict__ mri,
                                                   const float* __restrict__ pet,
                                                   float* __restrict__ pooledP) {
    const int blk  = blockIdx.x;          // 0..2047
    const int pair = blk >> 1;            // 0..1023
    const int half = blk & 1;
    const size_t base = (size_t)pair * SPATIAL + (size_t)half * HALF_F;
    const float4* m4 = (const float4*)(mri + base);
    const float4* p4 = (const float4*)(pet + base);
    const int t = threadIdx.x;

    float sm0 = 0.f, sm1 = 0.f, sp0 = 0.f, sp1 = 0.f;
    #pragma unroll
    for (int u = 0; u < 3; ++u) {         // 3 * 512 = 1536 float4 per stream
        const int i0 = u * 512 + t;
        const int i1 = i0 + 256;
        float4 a = m4[i0];
        float4 b = p4[i0];
        float4 c = m4[i1];
        float4 d = p4[i1];
        sm0 += a.x + a.y + a.z + a.w;
        sp0 += b.x + b.y + b.z + b.w;
        sm1 += c.x + c.y + c.z + c.w;
        sp1 += d.x + d.y + d.z + d.w;
    }
    if (t < HALF_V4 - 1536) {             // tail: 192 float4 per stream
        float4 a = m4[1536 + t];
        float4 b = p4[1536 + t];
        sm0 += a.x + a.y + a.z + a.w;
        sp0 += b.x + b.y + b.z + b.w;
    }
    float sm = sm0 + sm1, sp = sp0 + sp1;

    #pragma unroll
    for (int off = 32; off; off >>= 1) {
        sm += __shfl_down(sm, off, 64);
        sp += __shfl_down(sp, off, 64);
    }

    __shared__ float smM[4], smP[4];
    const int lane = t & 63, wv = t >> 6;
    if (lane == 0) { smM[wv] = sm; smP[wv] = sp; }
    __syncthreads();
    if (t == 0) {
        const float sc = 1.0f / SPATIAL;
        // layout: pooledP[mod][pair][half] as floats
        pooledP[(0 * 1024 + pair) * 2 + half] = (smM[0]+smM[1]+smM[2]+smM[3]) * sc;
        pooledP[(1 * 1024 + pair) * 2 + half] = (smP[0]+smP[1]+smP[2]+smP[3]) * sc;
    }
}

// ---------------------------------------------------------------------------
// Kernel B1: vt[b][j] = sum_c Wv_mri[j,c]*pm[b,c] + Wv_pet[j,c]*pp[b,c]
// pm/pp reconstructed by summing the two halves (float2 per (mod,pair)).
// 16 blocks x 256 thr.
// ---------------------------------------------------------------------------
__global__ __launch_bounds__(256) void vt_kernel(const float* __restrict__ pooledP,
                                                 const float* __restrict__ Wv_mri,
                                                 const float* __restrict__ Wv_pet,
                                                 float* __restrict__ vt) {
    __shared__ float pm[CIN], pp[CIN];
    const int b = blockIdx.x >> 1;                            // 0..7
    const int jbase = (blockIdx.x & 1) << 8;                  // 0 or 256
    const int t = threadIdx.x;
    const float2* P2 = (const float2*)pooledP;                // [mod][1024]
    if (t < CIN) {
        float2 v = P2[b * CIN + t];
        pm[t] = v.x + v.y;
    } else if (t < 2 * CIN) {
        const int c = t - CIN;
        float2 v = P2[1024 + b * CIN + c];
        pp[c] = v.x + v.y;
    }
    __syncthreads();

    const int j = jbase + t;
    const float4* wm4 = (const float4*)(Wv_mri + (size_t)j * CIN);
    const float4* wp4 = (const float4*)(Wv_pet + (size_t)j * CIN);
    float s = 0.f;
    #pragma unroll
    for (int c4 = 0; c4 < CIN / 4; ++c4) {
        float4 a = wm4[c4], q = wp4[c4];
        s += a.x * pm[c4*4+0] + a.y * pm[c4*4+1] + a.z * pm[c4*4+2] + a.w * pm[c4*4+3];
        s += q.x * pp[c4*4+0] + q.y * pp[c4*4+1] + q.z * pp[c4*4+2] + q.w * pp[c4*4+3];
    }
    vt[b * INNER + j] = s;
}

// ---------------------------------------------------------------------------
// Kernel B2: w[b][d] = bout[d] + Wout[d,:] . vt[b,:]
// One WAVE per d-row: 128 blocks x 256 thr (4 waves).
// ---------------------------------------------------------------------------
__global__ __launch_bounds__(256) void w_kernel(const float* __restrict__ vt,
                                                const float* __restrict__ Wout,
                                                const float* __restrict__ bout,
                                                float* __restrict__ w) {
    const int wv   = threadIdx.x >> 6;            // wave 0..3
    const int lane = threadIdx.x & 63;
    const int d    = blockIdx.x * 4 + wv;         // 0..511

    const float4* wo4 = (const float4*)(Wout + (size_t)d * INNER + lane * 8);
    float4 w0 = wo4[0], w1 = wo4[1];

    float acc[BN];
    #pragma unroll
    for (int b = 0; b < BN; ++b) {
        const float4* v4 = (const float4*)(vt + (size_t)b * INNER + lane * 8);
        float4 a = v4[0], c = v4[1];
        acc[b] = w0.x*a.x + w0.y*a.y + w0.z*a.z + w0.w*a.w
               + w1.x*c.x + w1.y*c.y + w1.z*c.z + w1.w*c.w;
    }
    #pragma unroll
    for (int off = 32; off; off >>= 1) {
        #pragma unroll
        for (int b = 0; b < BN; ++b) acc[b] += __shfl_xor(acc[b], off, 64);
    }
    if (lane < BN)
        w[lane * DIM + d] = acc[lane] + bout[d];
}

// ---------------------------------------------------------------------------
// Kernel C: out[b,n,:] = h_latent[b,n,:] + w[b,:]   (34 MB, BW-bound)
// Nontemporal stores: out is never re-read by us -> skip L3 allocation.
// ---------------------------------------------------------------------------
__global__ __launch_bounds__(256) void add_kernel(const float* __restrict__ h,
                                                  const float* __restrict__ w,
                                                  float* __restrict__ out) {
    const size_t i = (size_t)blockIdx.x * 256 + threadIdx.x;  // float4 index
    const int b  = (int)(i >> 17);      // / (1024*512/4)
    const int d4 = (int)(i & 127);      // float4 index within DIM
    float4 hv = ((const float4*)h)[i];
    float4 wv = ((const float4*)(w + (size_t)b * DIM))[d4];
    floatx4 o = { hv.x + wv.x, hv.y + wv.y, hv.z + wv.z, hv.w + wv.w };
    __builtin_nontemporal_store(o, &((floatx4*)out)[i]);
}

extern "C" void kernel_launch(void* const* d_in, const int* in_sizes, int n_in,
                              void* d_out, int out_size, void* d_ws, size_t ws_size,
                              hipStream_t stream) {
    const float* h_latent = (const float*)d_in[0];
    const float* h_mri    = (const float*)d_in[1];
    const float* h_pet    = (const float*)d_in[2];
    // d_in[3..5] = Wq, Wk_mri, Wk_pet — dead: softmax over a single KV token == 1.
    const float* Wv_mri   = (const float*)d_in[6];
    const float* Wv_pet   = (const float*)d_in[7];
    const float* Wout     = (const float*)d_in[8];
    const float* bout     = (const float*)d_in[9];
    float* out = (float*)d_out;

    // workspace (floats): pooledP[2][1024][2] @ 0, vt[8][512] @ 4096, w[8][512] @ 8192
    float* pooledP = (float*)d_ws;
    float* vt      = pooledP + 2 * 1024 * 2;
    float* w       = vt + BN * INNER;

    pool_kernel<<<2048, 256, 0, stream>>>(h_mri, h_pet, pooledP);
    vt_kernel<<<2 * BN, 256, 0, stream>>>(pooledP, Wv_mri, Wv_pet, vt);
    w_kernel<<<DIM / 4, 256, 0, stream>>>(vt, Wout, bout, w);
    add_kernel<<<(BN * NTOK * DIM / 4) / 256, 256, 0, stream>>>(h_latent, w, out);
}

// Round 11
// 173.143 us; speedup vs baseline: 1.0497x; 1.0497x over previous
//
#include <hip/hip_runtime.h>

// Shapes (fixed by the problem)
#define BN      8
#define NTOK    1024
#define DIM     512
#define INNER   512
#define CIN     128
#define SPATIAL 13824   // 24*24*24
#define HALF_F  6912    // SPATIAL/2 floats
#define HALF_V4 1728    // HALF_F/4 float4

// native clang vector type: __builtin_nontemporal_{load,store} reject HIP's
// float4 (a HIP_vector_type class). Same 16-byte layout.
typedef float floatx4 __attribute__((ext_vector_type(4)));

// ---------------------------------------------------------------------------
// Kernel A: partial pooled sums. Block = (pair, half); two address streams
// (mri+pet halves) per thread, 4 accumulators. R7+R10 lesson: per-thread MLP
// (1-stream and 2-stream unrolls) is NOT the limiter — pool pinned at ~40us
// = 2.80 TB/s read. R11 probe: NONTEMPORAL loads (read-once data) to test
// whether L2/L3 allocation/probe overhead is the read-path cost.
// ---------------------------------------------------------------------------
__global__ __launch_bounds__(256) void pool_kernel(const float* __restrict__ mri,
                                                   const float* __restrict__ pet,
                                                   float* __restrict__ pooledP) {
    const int blk  = blockIdx.x;          // 0..2047
    const int pair = blk >> 1;            // 0..1023
    const int half = blk & 1;
    const size_t base = (size_t)pair * SPATIAL + (size_t)half * HALF_F;
    const floatx4* m4 = (const floatx4*)(mri + base);
    const floatx4* p4 = (const floatx4*)(pet + base);
    const int t = threadIdx.x;

    float sm0 = 0.f, sm1 = 0.f, sp0 = 0.f, sp1 = 0.f;
    #pragma unroll
    for (int u = 0; u < 3; ++u) {         // 3 * 512 = 1536 float4 per stream
        const int i0 = u * 512 + t;
        const int i1 = i0 + 256;
        floatx4 a = __builtin_nontemporal_load(m4 + i0);
        floatx4 b = __builtin_nontemporal_load(p4 + i0);
        floatx4 c = __builtin_nontemporal_load(m4 + i1);
        floatx4 d = __builtin_nontemporal_load(p4 + i1);
        sm0 += a.x + a.y + a.z + a.w;
        sp0 += b.x + b.y + b.z + b.w;
        sm1 += c.x + c.y + c.z + c.w;
        sp1 += d.x + d.y + d.z + d.w;
    }
    if (t < HALF_V4 - 1536) {             // tail: 192 float4 per stream
        floatx4 a = __builtin_nontemporal_load(m4 + 1536 + t);
        floatx4 b = __builtin_nontemporal_load(p4 + 1536 + t);
        sm0 += a.x + a.y + a.z + a.w;
        sp0 += b.x + b.y + b.z + b.w;
    }
    float sm = sm0 + sm1, sp = sp0 + sp1;

    #pragma unroll
    for (int off = 32; off; off >>= 1) {
        sm += __shfl_down(sm, off, 64);
        sp += __shfl_down(sp, off, 64);
    }

    __shared__ float smM[4], smP[4];
    const int lane = t & 63, wv = t >> 6;
    if (lane == 0) { smM[wv] = sm; smP[wv] = sp; }
    __syncthreads();
    if (t == 0) {
        const float sc = 1.0f / SPATIAL;
        // layout: pooledP[mod][pair][half] as floats
        pooledP[(0 * 1024 + pair) * 2 + half] = (smM[0]+smM[1]+smM[2]+smM[3]) * sc;
        pooledP[(1 * 1024 + pair) * 2 + half] = (smP[0]+smP[1]+smP[2]+smP[3]) * sc;
    }
}

// ---------------------------------------------------------------------------
// Kernel B1: vt[b][j] = sum_c Wv_mri[j,c]*pm[b,c] + Wv_pet[j,c]*pp[b,c]
// pm/pp reconstructed by summing the two halves (float2 per (mod,pair)).
// 16 blocks x 256 thr.
// ---------------------------------------------------------------------------
__global__ __launch_bounds__(256) void vt_kernel(const float* __restrict__ pooledP,
                                                 const float* __restrict__ Wv_mri,
                                                 const float* __restrict__ Wv_pet,
                                                 float* __restrict__ vt) {
    __shared__ float pm[CIN], pp[CIN];
    const int b = blockIdx.x >> 1;                            // 0..7
    const int jbase = (blockIdx.x & 1) << 8;                  // 0 or 256
    const int t = threadIdx.x;
    const float2* P2 = (const float2*)pooledP;                // [mod][1024]
    if (t < CIN) {
        float2 v = P2[b * CIN + t];
        pm[t] = v.x + v.y;
    } else if (t < 2 * CIN) {
        const int c = t - CIN;
        float2 v = P2[1024 + b * CIN + c];
        pp[c] = v.x + v.y;
    }
    __syncthreads();

    const int j = jbase + t;
    const float4* wm4 = (const float4*)(Wv_mri + (size_t)j * CIN);
    const float4* wp4 = (const float4*)(Wv_pet + (size_t)j * CIN);
    float s = 0.f;
    #pragma unroll
    for (int c4 = 0; c4 < CIN / 4; ++c4) {
        float4 a = wm4[c4], q = wp4[c4];
        s += a.x * pm[c4*4+0] + a.y * pm[c4*4+1] + a.z * pm[c4*4+2] + a.w * pm[c4*4+3];
        s += q.x * pp[c4*4+0] + q.y * pp[c4*4+1] + q.z * pp[c4*4+2] + q.w * pp[c4*4+3];
    }
    vt[b * INNER + j] = s;
}

// ---------------------------------------------------------------------------
// Kernel B2: w[b][d] = bout[d] + Wout[d,:] . vt[b,:]
// One WAVE per d-row: 128 blocks x 256 thr (4 waves).
// ---------------------------------------------------------------------------
__global__ __launch_bounds__(256) void w_kernel(const float* __restrict__ vt,
                                                const float* __restrict__ Wout,
                                                const float* __restrict__ bout,
                                                float* __restrict__ w) {
    const int wv   = threadIdx.x >> 6;            // wave 0..3
    const int lane = threadIdx.x & 63;
    const int d    = blockIdx.x * 4 + wv;         // 0..511

    const float4* wo4 = (const float4*)(Wout + (size_t)d * INNER + lane * 8);
    float4 w0 = wo4[0], w1 = wo4[1];

    float acc[BN];
    #pragma unroll
    for (int b = 0; b < BN; ++b) {
        const float4* v4 = (const float4*)(vt + (size_t)b * INNER + lane * 8);
        float4 a = v4[0], c = v4[1];
        acc[b] = w0.x*a.x + w0.y*a.y + w0.z*a.z + w0.w*a.w
               + w1.x*c.x + w1.y*c.y + w1.z*c.z + w1.w*c.w;
    }
    #pragma unroll
    for (int off = 32; off; off >>= 1) {
        #pragma unroll
        for (int b = 0; b < BN; ++b) acc[b] += __shfl_xor(acc[b], off, 64);
    }
    if (lane < BN)
        w[lane * DIM + d] = acc[lane] + bout[d];
}

// ---------------------------------------------------------------------------
// Kernel C: out[b,n,:] = h_latent[b,n,:] + w[b,:]   (34 MB, BW-bound)
// Nontemporal stores: out is never re-read by us -> skip L3 allocation.
// ---------------------------------------------------------------------------
__global__ __launch_bounds__(256) void add_kernel(const float* __restrict__ h,
                                                  const float* __restrict__ w,
                                                  float* __restrict__ out) {
    const size_t i = (size_t)blockIdx.x * 256 + threadIdx.x;  // float4 index
    const int b  = (int)(i >> 17);      // / (1024*512/4)
    const int d4 = (int)(i & 127);      // float4 index within DIM
    float4 hv = ((const float4*)h)[i];
    float4 wv = ((const float4*)(w + (size_t)b * DIM))[d4];
    floatx4 o = { hv.x + wv.x, hv.y + wv.y, hv.z + wv.z, hv.w + wv.w };
    __builtin_nontemporal_store(o, &((floatx4*)out)[i]);
}

extern "C" void kernel_launch(void* const* d_in, const int* in_sizes, int n_in,
                              void* d_out, int out_size, void* d_ws, size_t ws_size,
                              hipStream_t stream) {
    const float* h_latent = (const float*)d_in[0];
    const float* h_mri    = (const float*)d_in[1];
    const float* h_pet    = (const float*)d_in[2];
    // d_in[3..5] = Wq, Wk_mri, Wk_pet — dead: softmax over a single KV token == 1.
    const float* Wv_mri   = (const float*)d_in[6];
    const float* Wv_pet   = (const float*)d_in[7];
    const float* Wout     = (const float*)d_in[8];
    const float* bout     = (const float*)d_in[9];
    float* out = (float*)d_out;

    // workspace (floats): pooledP[2][1024][2] @ 0, vt[8][512] @ 4096, w[8][512] @ 8192
    float* pooledP = (float*)d_ws;
    float* vt      = pooledP + 2 * 1024 * 2;
    float* w       = vt + BN * INNER;

    pool_kernel<<<2048, 256, 0, stream>>>(h_mri, h_pet, pooledP);
    vt_kernel<<<2 * BN, 256, 0, stream>>>(pooledP, Wv_mri, Wv_pet, vt);
    w_kernel<<<DIM / 4, 256, 0, stream>>>(vt, Wout, bout, w);
    add_kernel<<<(BN * NTOK * DIM / 4) / 256, 256, 0, stream>>>(h_latent, w, out);
}

// Round 14
// 171.356 us; speedup vs baseline: 1.0606x; 1.0104x over previous
//
#include <hip/hip_runtime.h>

// Shapes (fixed by the problem)
#define BN      8
#define NTOK    1024
#define DIM     512
#define INNER   512
#define CIN     128
#define SPATIAL 13824   // 24*24*24
#define HALF_F  6912    // SPATIAL/2 floats
#define HALF_V4 1728    // HALF_F/4 float4

// native clang vector type: __builtin_nontemporal_{load,store} reject HIP's
// float4 (a HIP_vector_type class). Same 16-byte layout.
typedef float floatx4 __attribute__((ext_vector_type(4)));

// ---------------------------------------------------------------------------
// Kernel A: partial pooled sums. Block = (pair, half); streams = mri-half +
// pet-half. R11: nt loads gave 40.5 -> ~31.5us (3.6 TB/s HBM-direct read;
// the L3-mixed path was slower). R12 probe: 6 independent nt loads in flight
// per iteration (was 4) — deeper MLP under the longer nt (no-L3) latency.
// If null: ~3.6 TB/s is the empirical streaming-read ceiling here.
// ---------------------------------------------------------------------------
__global__ __launch_bounds__(256) void pool_kernel(const float* __restrict__ mri,
                                                   const float* __restrict__ pet,
                                                   float* __restrict__ pooledP) {
    const int blk  = blockIdx.x;          // 0..2047
    const int pair = blk >> 1;            // 0..1023
    const int half = blk & 1;
    const size_t base = (size_t)pair * SPATIAL + (size_t)half * HALF_F;
    const floatx4* m4 = (const floatx4*)(mri + base);
    const floatx4* p4 = (const floatx4*)(pet + base);
    const int t = threadIdx.x;

    float sm0 = 0.f, sm1 = 0.f, sm2 = 0.f;
    float sp0 = 0.f, sp1 = 0.f, sp2 = 0.f;
    #pragma unroll
    for (int u = 0; u < 2; ++u) {         // 2 * 768 = 1536 float4 per stream
        const int i0 = u * 768 + t;
        floatx4 a = __builtin_nontemporal_load(m4 + i0);
        floatx4 b = __builtin_nontemporal_load(m4 + i0 + 256);
        floatx4 c = __builtin_nontemporal_load(m4 + i0 + 512);
        floatx4 d = __builtin_nontemporal_load(p4 + i0);
        floatx4 e = __builtin_nontemporal_load(p4 + i0 + 256);
        floatx4 f = __builtin_nontemporal_load(p4 + i0 + 512);
        sm0 += a.x + a.y + a.z + a.w;
        sm1 += b.x + b.y + b.z + b.w;
        sm2 += c.x + c.y + c.z + c.w;
        sp0 += d.x + d.y + d.z + d.w;
        sp1 += e.x + e.y + e.z + e.w;
        sp2 += f.x + f.y + f.z + f.w;
    }
    if (t < HALF_V4 - 1536) {             // tail: 192 float4 per stream
        floatx4 a = __builtin_nontemporal_load(m4 + 1536 + t);
        floatx4 b = __builtin_nontemporal_load(p4 + 1536 + t);
        sm0 += a.x + a.y + a.z + a.w;
        sp0 += b.x + b.y + b.z + b.w;
    }
    float sm = (sm0 + sm1) + sm2;
    float sp = (sp0 + sp1) + sp2;

    #pragma unroll
    for (int off = 32; off; off >>= 1) {
        sm += __shfl_down(sm, off, 64);
        sp += __shfl_down(sp, off, 64);
    }

    __shared__ float smM[4], smP[4];
    const int lane = t & 63, wv = t >> 6;
    if (lane == 0) { smM[wv] = sm; smP[wv] = sp; }
    __syncthreads();
    if (t == 0) {
        const float sc = 1.0f / SPATIAL;
        // layout: pooledP[mod][pair][half] as floats
        pooledP[(0 * 1024 + pair) * 2 + half] = (smM[0]+smM[1]+smM[2]+smM[3]) * sc;
        pooledP[(1 * 1024 + pair) * 2 + half] = (smP[0]+smP[1]+smP[2]+smP[3]) * sc;
    }
}

// ---------------------------------------------------------------------------
// Kernel B1: vt[b][j] = sum_c Wv_mri[j,c]*pm[b,c] + Wv_pet[j,c]*pp[b,c]
// pm/pp reconstructed by summing the two halves (float2 per (mod,pair)).
// 16 blocks x 256 thr.
// ---------------------------------------------------------------------------
__global__ __launch_bounds__(256) void vt_kernel(const float* __restrict__ pooledP,
                                                 const float* __restrict__ Wv_mri,
                                                 const float* __restrict__ Wv_pet,
                                                 float* __restrict__ vt) {
    __shared__ float pm[CIN], pp[CIN];
    const int b = blockIdx.x >> 1;                            // 0..7
    const int jbase = (blockIdx.x & 1) << 8;                  // 0 or 256
    const int t = threadIdx.x;
    const float2* P2 = (const float2*)pooledP;                // [mod][1024]
    if (t < CIN) {
        float2 v = P2[b * CIN + t];
        pm[t] = v.x + v.y;
    } else if (t < 2 * CIN) {
        const int c = t - CIN;
        float2 v = P2[1024 + b * CIN + c];
        pp[c] = v.x + v.y;
    }
    __syncthreads();

    const int j = jbase + t;
    const float4* wm4 = (const float4*)(Wv_mri + (size_t)j * CIN);
    const float4* wp4 = (const float4*)(Wv_pet + (size_t)j * CIN);
    float s = 0.f;
    #pragma unroll
    for (int c4 = 0; c4 < CIN / 4; ++c4) {
        float4 a = wm4[c4], q = wp4[c4];
        s += a.x * pm[c4*4+0] + a.y * pm[c4*4+1] + a.z * pm[c4*4+2] + a.w * pm[c4*4+3];
        s += q.x * pp[c4*4+0] + q.y * pp[c4*4+1] + q.z * pp[c4*4+2] + q.w * pp[c4*4+3];
    }
    vt[b * INNER + j] = s;
}

// ---------------------------------------------------------------------------
// Kernel B2: w[b][d] = bout[d] + Wout[d,:] . vt[b,:]
// One WAVE per d-row: 128 blocks x 256 thr (4 waves).
// ---------------------------------------------------------------------------
__global__ __launch_bounds__(256) void w_kernel(const float* __restrict__ vt,
                                                const float* __restrict__ Wout,
                                                const float* __restrict__ bout,
                                                float* __restrict__ w) {
    const int wv   = threadIdx.x >> 6;            // wave 0..3
    const int lane = threadIdx.x & 63;
    const int d    = blockIdx.x * 4 + wv;         // 0..511

    const float4* wo4 = (const float4*)(Wout + (size_t)d * INNER + lane * 8);
    float4 w0 = wo4[0], w1 = wo4[1];

    float acc[BN];
    #pragma unroll
    for (int b = 0; b < BN; ++b) {
        const float4* v4 = (const float4*)(vt + (size_t)b * INNER + lane * 8);
        float4 a = v4[0], c = v4[1];
        acc[b] = w0.x*a.x + w0.y*a.y + w0.z*a.z + w0.w*a.w
               + w1.x*c.x + w1.y*c.y + w1.z*c.z + w1.w*c.w;
    }
    #pragma unroll
    for (int off = 32; off; off >>= 1) {
        #pragma unroll
        for (int b = 0; b < BN; ++b) acc[b] += __shfl_xor(acc[b], off, 64);
    }
    if (lane < BN)
        w[lane * DIM + d] = acc[lane] + bout[d];
}

// ---------------------------------------------------------------------------
// Kernel C: out[b,n,:] = h_latent[b,n,:] + w[b,:]   (34 MB, BW-bound)
// nt load for h (read-once) + nt store for out (never re-read) — same
// mechanism that won R11 on pool.
// ---------------------------------------------------------------------------
__global__ __launch_bounds__(256) void add_kernel(const float* __restrict__ h,
                                                  const float* __restrict__ w,
                                                  float* __restrict__ out) {
    const size_t i = (size_t)blockIdx.x * 256 + threadIdx.x;  // float4 index
    const int b  = (int)(i >> 17);      // / (1024*512/4)
    const int d4 = (int)(i & 127);      // float4 index within DIM
    floatx4 hv = __builtin_nontemporal_load(&((const floatx4*)h)[i]);
    float4  wv = ((const float4*)(w + (size_t)b * DIM))[d4];
    floatx4 o = { hv.x + wv.x, hv.y + wv.y, hv.z + wv.z, hv.w + wv.w };
    __builtin_nontemporal_store(o, &((floatx4*)out)[i]);
}

extern "C" void kernel_launch(void* const* d_in, const int* in_sizes, int n_in,
                              void* d_out, int out_size, void* d_ws, size_t ws_size,
                              hipStream_t stream) {
    const float* h_latent = (const float*)d_in[0];
    const float* h_mri    = (const float*)d_in[1];
    const float* h_pet    = (const float*)d_in[2];
    // d_in[3..5] = Wq, Wk_mri, Wk_pet — dead: softmax over a single KV token == 1.
    const float* Wv_mri   = (const float*)d_in[6];
    const float* Wv_pet   = (const float*)d_in[7];
    const float* Wout     = (const float*)d_in[8];
    const float* bout     = (const float*)d_in[9];
    float* out = (float*)d_out;

    // workspace (floats): pooledP[2][1024][2] @ 0, vt[8][512] @ 4096, w[8][512] @ 8192
    float* pooledP = (float*)d_ws;
    float* vt      = pooledP + 2 * 1024 * 2;
    float* w       = vt + BN * INNER;

    pool_kernel<<<2048, 256, 0, stream>>>(h_mri, h_pet, pooledP);
    vt_kernel<<<2 * BN, 256, 0, stream>>>(pooledP, Wv_mri, Wv_pet, vt);
    w_kernel<<<DIM / 4, 256, 0, stream>>>(vt, Wout, bout, w);
    add_kernel<<<(BN * NTOK * DIM / 4) / 256, 256, 0, stream>>>(h_latent, w, out);
}

// Round 16
// 166.531 us; speedup vs baseline: 1.0914x; 1.0290x over previous
//
#include <hip/hip_runtime.h>

// Shapes (fixed by the problem)
#define BN      8
#define NTOK    1024
#define DIM     512
#define INNER   512
#define CIN     128
#define SPATIAL 13824   // 24*24*24
#define HALF_F  6912    // SPATIAL/2 floats
#define HALF_V4 1728    // HALF_F/4 float4

// native clang vector type: __builtin_nontemporal_{load,store} reject HIP's
// float4 (a HIP_vector_type class). Same 16-byte layout.
typedef float floatx4 __attribute__((ext_vector_type(4)));

// ---------------------------------------------------------------------------
// Kernel A: partial pooled sums. Block = (pair, half); streams = mri-half +
// pet-half. Ladder: cached 2.80 TB/s (R5) -> nt 3.59 TB/s (R11); MLP probes
// null x3 (R7/R10/R14). R15 probe: PATH ADDITIVITY — pet via NORMAL cached
// loads (L3-resident from harness restore, ~50% hit per R5), mri stays NT
// (HBM-direct). If L3 and HBM read paths add, pool < 27us; if null, the
// read-path ceiling is confirmed -> roofline.
// ---------------------------------------------------------------------------
__global__ __launch_bounds__(256) void pool_kernel(const float* __restrict__ mri,
                                                   const float* __restrict__ pet,
                                                   float* __restrict__ pooledP) {
    const int blk  = blockIdx.x;          // 0..2047
    const int pair = blk >> 1;            // 0..1023
    const int half = blk & 1;
    const size_t base = (size_t)pair * SPATIAL + (size_t)half * HALF_F;
    const floatx4* m4 = (const floatx4*)(mri + base);
    const floatx4* p4 = (const floatx4*)(pet + base);
    const int t = threadIdx.x;

    float sm0 = 0.f, sm1 = 0.f, sm2 = 0.f;
    float sp0 = 0.f, sp1 = 0.f, sp2 = 0.f;
    #pragma unroll
    for (int u = 0; u < 2; ++u) {         // 2 * 768 = 1536 float4 per stream
        const int i0 = u * 768 + t;
        floatx4 a = __builtin_nontemporal_load(m4 + i0);
        floatx4 b = __builtin_nontemporal_load(m4 + i0 + 256);
        floatx4 c = __builtin_nontemporal_load(m4 + i0 + 512);
        floatx4 d = p4[i0];               // normal cached (L3-hit candidate)
        floatx4 e = p4[i0 + 256];
        floatx4 f = p4[i0 + 512];
        sm0 += a.x + a.y + a.z + a.w;
        sm1 += b.x + b.y + b.z + b.w;
        sm2 += c.x + c.y + c.z + c.w;
        sp0 += d.x + d.y + d.z + d.w;
        sp1 += e.x + e.y + e.z + e.w;
        sp2 += f.x + f.y + f.z + f.w;
    }
    if (t < HALF_V4 - 1536) {             // tail: 192 float4 per stream
        floatx4 a = __builtin_nontemporal_load(m4 + 1536 + t);
        floatx4 b = p4[1536 + t];
        sm0 += a.x + a.y + a.z + a.w;
        sp0 += b.x + b.y + b.z + b.w;
    }
    float sm = (sm0 + sm1) + sm2;
    float sp = (sp0 + sp1) + sp2;

    #pragma unroll
    for (int off = 32; off; off >>= 1) {
        sm += __shfl_down(sm, off, 64);
        sp += __shfl_down(sp, off, 64);
    }

    __shared__ float smM[4], smP[4];
    const int lane = t & 63, wv = t >> 6;
    if (lane == 0) { smM[wv] = sm; smP[wv] = sp; }
    __syncthreads();
    if (t == 0) {
        const float sc = 1.0f / SPATIAL;
        // layout: pooledP[mod][pair][half] as floats
        pooledP[(0 * 1024 + pair) * 2 + half] = (smM[0]+smM[1]+smM[2]+smM[3]) * sc;
        pooledP[(1 * 1024 + pair) * 2 + half] = (smP[0]+smP[1]+smP[2]+smP[3]) * sc;
    }
}

// ---------------------------------------------------------------------------
// Kernel B1: vt[b][j] = sum_c Wv_mri[j,c]*pm[b,c] + Wv_pet[j,c]*pp[b,c]
// pm/pp reconstructed by summing the two halves (float2 per (mod,pair)).
// 16 blocks x 256 thr.
// ---------------------------------------------------------------------------
__global__ __launch_bounds__(256) void vt_kernel(const float* __restrict__ pooledP,
                                                 const float* __restrict__ Wv_mri,
                                                 const float* __restrict__ Wv_pet,
                                                 float* __restrict__ vt) {
    __shared__ float pm[CIN], pp[CIN];
    const int b = blockIdx.x >> 1;                            // 0..7
    const int jbase = (blockIdx.x & 1) << 8;                  // 0 or 256
    const int t = threadIdx.x;
    const float2* P2 = (const float2*)pooledP;                // [mod][1024]
    if (t < CIN) {
        float2 v = P2[b * CIN + t];
        pm[t] = v.x + v.y;
    } else if (t < 2 * CIN) {
        const int c = t - CIN;
        float2 v = P2[1024 + b * CIN + c];
        pp[c] = v.x + v.y;
    }
    __syncthreads();

    const int j = jbase + t;
    const float4* wm4 = (const float4*)(Wv_mri + (size_t)j * CIN);
    const float4* wp4 = (const float4*)(Wv_pet + (size_t)j * CIN);
    float s = 0.f;
    #pragma unroll
    for (int c4 = 0; c4 < CIN / 4; ++c4) {
        float4 a = wm4[c4], q = wp4[c4];
        s += a.x * pm[c4*4+0] + a.y * pm[c4*4+1] + a.z * pm[c4*4+2] + a.w * pm[c4*4+3];
        s += q.x * pp[c4*4+0] + q.y * pp[c4*4+1] + q.z * pp[c4*4+2] + q.w * pp[c4*4+3];
    }
    vt[b * INNER + j] = s;
}

// ---------------------------------------------------------------------------
// Kernel B2: w[b][d] = bout[d] + Wout[d,:] . vt[b,:]
// One WAVE per d-row: 128 blocks x 256 thr (4 waves).
// ---------------------------------------------------------------------------
__global__ __launch_bounds__(256) void w_kernel(const float* __restrict__ vt,
                                                const float* __restrict__ Wout,
                                                const float* __restrict__ bout,
                                                float* __restrict__ w) {
    const int wv   = threadIdx.x >> 6;            // wave 0..3
    const int lane = threadIdx.x & 63;
    const int d    = blockIdx.x * 4 + wv;         // 0..511

    const float4* wo4 = (const float4*)(Wout + (size_t)d * INNER + lane * 8);
    float4 w0 = wo4[0], w1 = wo4[1];

    float acc[BN];
    #pragma unroll
    for (int b = 0; b < BN; ++b) {
        const float4* v4 = (const float4*)(vt + (size_t)b * INNER + lane * 8);
        float4 a = v4[0], c = v4[1];
        acc[b] = w0.x*a.x + w0.y*a.y + w0.z*a.z + w0.w*a.w
               + w1.x*c.x + w1.y*c.y + w1.z*c.z + w1.w*c.w;
    }
    #pragma unroll
    for (int off = 32; off; off >>= 1) {
        #pragma unroll
        for (int b = 0; b < BN; ++b) acc[b] += __shfl_xor(acc[b], off, 64);
    }
    if (lane < BN)
        w[lane * DIM + d] = acc[lane] + bout[d];
}

// ---------------------------------------------------------------------------
// Kernel C: out[b,n,:] = h_latent[b,n,:] + w[b,:]   (34 MB, BW-bound)
// nt load for h (read-once) + nt store for out (never re-read). ~6.2 TB/s
// combined (R14) ~= m13 copy ceiling.
// ---------------------------------------------------------------------------
__global__ __launch_bounds__(256) void add_kernel(const float* __restrict__ h,
                                                  const float* __restrict__ w,
                                                  float* __restrict__ out) {
    const size_t i = (size_t)blockIdx.x * 256 + threadIdx.x;  // float4 index
    const int b  = (int)(i >> 17);      // / (1024*512/4)
    const int d4 = (int)(i & 127);      // float4 index within DIM
    floatx4 hv = __builtin_nontemporal_load(&((const floatx4*)h)[i]);
    float4  wv = ((const float4*)(w + (size_t)b * DIM))[d4];
    floatx4 o = { hv.x + wv.x, hv.y + wv.y, hv.z + wv.z, hv.w + wv.w };
    __builtin_nontemporal_store(o, &((floatx4*)out)[i]);
}

extern "C" void kernel_launch(void* const* d_in, const int* in_sizes, int n_in,
                              void* d_out, int out_size, void* d_ws, size_t ws_size,
                              hipStream_t stream) {
    const float* h_latent = (const float*)d_in[0];
    const float* h_mri    = (const float*)d_in[1];
    const float* h_pet    = (const float*)d_in[2];
    // d_in[3..5] = Wq, Wk_mri, Wk_pet — dead: softmax over a single KV token == 1.
    const float* Wv_mri   = (const float*)d_in[6];
    const float* Wv_pet   = (const float*)d_in[7];
    const float* Wout     = (const float*)d_in[8];
    const float* bout     = (const float*)d_in[9];
    float* out = (float*)d_out;

    // workspace (floats): pooledP[2][1024][2] @ 0, vt[8][512] @ 4096, w[8][512] @ 8192
    float* pooledP = (float*)d_ws;
    float* vt      = pooledP + 2 * 1024 * 2;
    float* w       = vt + BN * INNER;

    pool_kernel<<<2048, 256, 0, stream>>>(h_mri, h_pet, pooledP);
    vt_kernel<<<2 * BN, 256, 0, stream>>>(pooledP, Wv_mri, Wv_pet, vt);
    w_kernel<<<DIM / 4, 256, 0, stream>>>(vt, Wout, bout, w);
    add_kernel<<<(BN * NTOK * DIM / 4) / 256, 256, 0, stream>>>(h_latent, w, out);
}